// Round 1
// baseline (270.627 us; speedup 1.0000x reference)
//
#include <hip/hip_runtime.h>

#define NB 4                 // batch
#define GRID_X 640
#define NCELL (GRID_X*GRID_X)      // 409600
#define NWORD (NCELL/32)           // 12800 bitmask words per sample
#define MAXPIL 12000
#define MAXPTS 100
#define SCAN_T 512
#define WPT (NWORD/SCAN_T)         // 25 words per scan thread

typedef unsigned short u16;
typedef unsigned int   u32;

// ---- bf16 round-trip (RTNE) — used ONLY for the pillar-id value write ----
__device__ __forceinline__ float bf16rt(float f) {
    u32 u = __builtin_bit_cast(u32, f);
    u32 r = ((u + 0x7FFFu + ((u >> 16) & 1u)) >> 16) << 16;
    return __builtin_bit_cast(float, r);
}

// value barrier: blocks -ffp-contract=fast from fusing mul into the following sub
__device__ __forceinline__ float opaquef(float x) { asm volatile("" : "+v"(x)); return x; }

// XLA constant-folded reciprocals (verified rounding by hand):
//   1/f32(102.4) rounds to exactly 0.009765625f (5/512)
//   1/f32(0.32f/102.4f) = 320*(1+2^-24) -> rounds UP to 320 + 2^-15
#define R102 0.009765625f
#define RWH  320.000030517578125f          // 0x1.400002p8
__device__ __host__ constexpr float WH_N_C() { return (2.0f*0.16f)/(51.2f-(-51.2f)); }

// XLA sequence: t=2*(v+51.2); p=t*R102 (rounded); xn=p-1 (rounded separately!)
__device__ __forceinline__ float norm_x(float v) {
    float p = 2.0f*(v + 51.2f) * R102;
    return opaquef(p) - 1.0f;
}
// z: divide by 8 == multiply by exact 0.125 — identical either way
__device__ __forceinline__ float norm_z(float v) {
    float p = 2.0f*(v + 5.0f) * 0.125f;
    return opaquef(p) - 1.0f;
}

__device__ __forceinline__ int cell_of(float xn, float yn) {
    float fx = fminf(fmaxf(floorf((xn + 1.0f) * RWH), 0.0f), 639.0f);  // fmax = inert safety clamp
    float fy = fminf(fmaxf(floorf((yn + 1.0f) * RWH), 0.0f), 639.0f);
    return (int)fy * GRID_X + (int)fx;
}

// ---- K0: zero occMask only (slotCnt zeroing + pillar defaults moved into k_scan) ----
__global__ void k_init(int4* __restrict__ zero4, int nz4) {
    int i = blockIdx.x*blockDim.x + threadIdx.x;
    if (i < nz4) zero4[i] = make_int4(0,0,0,0);
}

// ---- K1: per-point cell id (cached to ws) + occupancy bitmask ----
__global__ void k_mask(const float4* __restrict__ pc, int P, u32* __restrict__ occMask,
                       int* __restrict__ cellId) {
    int i = blockIdx.x*blockDim.x + threadIdx.x;
    if (i >= NB*P) return;
    float4 pt = pc[i];
    int cell = cell_of(norm_x(pt.x), norm_x(pt.y));
    cellId[i] = cell;
    int b = i / P;
    atomicOr(&occMask[b*NWORD + (cell >> 5)], 1u << (cell & 31));
}

// ---- K2 (fused scanA+B+C): one block per sample. 512 thr x 25 words, regs-resident.
//      popc -> block exclusive scan -> per-word prefixes + sorted pillar emit +
//      tail fill of slotCell/pillars_f + slotCnt zeroing. ----
__global__ __launch_bounds__(SCAN_T) void k_scan(const u32* __restrict__ occMask,
        int* __restrict__ wordPrefix, int* __restrict__ slotCnt,
        int* __restrict__ slotCell, float* __restrict__ pillars_f) {
    __shared__ int lds[SCAN_T];
    int b = blockIdx.x;
    int t = threadIdx.x;
    const u32* mask = occMask + b*NWORD;
    int base = t*WPT;
    u32 w[WPT];
#pragma unroll
    for (int i = 0; i < WPT; i++) w[i] = mask[base + i];
    // zero slotCnt while the mask loads are in flight
    for (int i = t; i < MAXPIL; i += SCAN_T) slotCnt[b*MAXPIL + i] = 0;
    int sum = 0;
#pragma unroll
    for (int i = 0; i < WPT; i++) sum += __popc(w[i]);
    lds[t] = sum;
    __syncthreads();
    for (int d = 1; d < SCAN_T; d <<= 1) {
        int v = (t >= d) ? lds[t - d] : 0;
        __syncthreads();
        lds[t] += v;
        __syncthreads();
    }
    int slot  = lds[t] - sum;            // exclusive prefix for this thread's chunk
    int total = lds[SCAN_T - 1];         // occupied pillars this sample
#pragma unroll
    for (int i = 0; i < WPT; i++) {
        int wi = base + i;
        wordPrefix[b*NWORD + wi] = slot;
        u32 m = w[i];
        int wbase = wi << 5;
        while (m) {
            int bit = __ffs(m) - 1;
            m &= m - 1;
            if (slot < MAXPIL) {
                int cell = wbase + bit;
                slotCell[b*MAXPIL + slot]  = cell;
                pillars_f[b*MAXPIL + slot] = bf16rt((float)cell);  // match bf16-cast expected
            }
            slot++;
        }
    }
    // tail: unused slots get id -1 / -1.0f
    for (int i = total + t; i < MAXPIL; i += SCAN_T) {
        slotCell[b*MAXPIL + i]  = -1;
        pillars_f[b*MAXPIL + i] = -1.0f;
    }
}

// ---- K3: scatter point indices into per-pillar lists (uses cached cellId) ----
__global__ void k_scatter(int P, const u32* __restrict__ occMask,
                          const int* __restrict__ wordPrefix, const int* __restrict__ cellId,
                          int* __restrict__ slotCnt, u16* __restrict__ idx16) {
    int i = blockIdx.x*blockDim.x + threadIdx.x;
    if (i >= NB*P) return;
    int b = i / P;
    int p = i - b*P;
    int cell = cellId[i];
    int w = cell >> 5, bit = cell & 31;
    u32 m = occMask[b*NWORD + w];
    int slot = wordPrefix[b*NWORD + w] + __popc(m & ((1u << bit) - 1u));
    if (slot >= MAXPIL) return;
    int g = b*MAXPIL + slot;
    int pos = atomicAdd(&slotCnt[g], 1);
    if (pos < MAXPTS) idx16[(size_t)g*MAXPTS + pos] = (u16)p;
}

// ---- K4: one wave per pillar: rank by index, build 100x9 f32 tile, dump ----
__global__ __launch_bounds__(64) void k_write(const float4* __restrict__ pc, int P,
                        const int* __restrict__ slotCell, const int* __restrict__ slotCnt,
                        const u16* __restrict__ idx16, float* __restrict__ out) {
    __shared__ __align__(16) float tile[MAXPTS*9];   // 900 f32 = 3600 B
    __shared__ int sIdx[MAXPTS];
    __shared__ float sx[MAXPTS], sy[MAXPTS], sz[MAXPTS], sr[MAXPTS];
    int g = blockIdx.x;                 // b*MAXPIL + slot
    int b = g / MAXPIL;
    int lane = threadIdx.x;
    float4* out4 = (float4*)out + (size_t)g*225;   // 225 x 16B per pillar
    int u = slotCell[g];
    if (u < 0) {                        // empty pillar: pure zero fill
        float4 z = make_float4(0.f,0.f,0.f,0.f);
        for (int i = lane; i < 225; i += 64) out4[i] = z;
        return;
    }
    int ntot = slotCnt[g];
    int n = min(ntot, MAXPTS);          // points/pillar ~5 here, so n == ntot

    float4* t4 = (float4*)tile;
    for (int i = lane; i < 225; i += 64) t4[i] = make_float4(0.f,0.f,0.f,0.f);

    // gather + normalize + local mean partials
    float ax = 0.f, ay = 0.f, az = 0.f;
    for (int j = lane; j < n; j += 64) {
        int p = idx16[(size_t)g*MAXPTS + j];
        sIdx[j] = p;
        float4 pt = pc[b*P + p];
        float xn = norm_x(pt.x);
        float yn = norm_x(pt.y);
        float zn = norm_z(pt.z);
        sx[j] = xn; sy[j] = yn; sz[j] = zn; sr[j] = pt.w;
        ax += xn; ay += yn; az += zn;
    }
    // wave-reduce means (f32; feature threshold is generous)
    for (int msk = 1; msk < 64; msk <<= 1) {
        ax += __shfl_xor(ax, msk);
        ay += __shfl_xor(ay, msk);
        az += __shfl_xor(az, msk);
    }
    float den = (float)max(ntot, 1);
    float mx = ax/den, my = ay/den, mz = az/den;
    const float wh = WH_N_C();
    float cx = -1.0f + (float)(u % GRID_X)*wh + wh*0.5f;
    float cy = -1.0f + (float)(u / GRID_X)*wh + wh*0.5f;
    __syncthreads();

    for (int j = lane; j < n; j += 64) {
        int p = sIdx[j];
        int rk = 0;                     // rank by original point index (stable order)
        for (int k = 0; k < n; k++) rk += (sIdx[k] < p) ? 1 : 0;
        float xn = sx[j], yn = sy[j], zn = sz[j];
        float* e = &tile[rk*9];
        e[0] = xn; e[1] = yn; e[2] = zn; e[3] = sr[j];
        e[4] = fabsf(xn - mx); e[5] = fabsf(yn - my); e[6] = fabsf(zn - mz);
        e[7] = cx - xn; e[8] = cy - yn;
    }
    __syncthreads();
    for (int i = lane; i < 225; i += 64) out4[i] = t4[i];
}

extern "C" void kernel_launch(void* const* d_in, const int* in_sizes, int n_in,
                              void* d_out, int out_size, void* d_ws, size_t ws_size,
                              hipStream_t stream) {
    const float4* pc = (const float4*)d_in[0];     // f32 x4 per point
    int P = in_sizes[0] / (NB*4);                  // 50000
    float* out = (float*)d_out;                    // f32 output buffer
    float* pillars_f = out + (size_t)NB*MAXPIL*MAXPTS*9;  // second tuple output (f32)

    // workspace layout (~11.2 MB total, int units)
    u32* occMask   = (u32*)d_ws;                        // NB*NWORD      = 51200
    int* slotCnt   = (int*)(occMask + NB*NWORD);        // NB*MAXPIL     = 48000
    int* wordPrefix= slotCnt + NB*MAXPIL;               // NB*NWORD      = 51200
    int* slotCell  = wordPrefix + NB*NWORD;             // NB*MAXPIL     = 48000
    int* cellId    = slotCell + NB*MAXPIL;              // NB*P          = 200000
    u16* idx16     = (u16*)(cellId + NB*P);             // NB*MAXPIL*MAXPTS u16 = 9.6 MB

    int nz4 = (NB*NWORD) / 4;                           // occMask int4 count = 12800

    k_init<<<(nz4+255)/256, 256, 0, stream>>>((int4*)occMask, nz4);
    k_mask<<<(NB*P+255)/256, 256, 0, stream>>>(pc, P, occMask, cellId);
    k_scan<<<NB, SCAN_T, 0, stream>>>(occMask, wordPrefix, slotCnt, slotCell, pillars_f);
    k_scatter<<<(NB*P+255)/256, 256, 0, stream>>>(P, occMask, wordPrefix, cellId, slotCnt, idx16);
    k_write<<<NB*MAXPIL, 64, 0, stream>>>(pc, P, slotCell, slotCnt, idx16, out);
}

// Round 2
// 225.500 us; speedup vs baseline: 1.2001x; 1.2001x over previous
//
#include <hip/hip_runtime.h>

#define NB 4                 // batch
#define GRID_X 640
#define NCELL (GRID_X*GRID_X)      // 409600
#define NWORD (NCELL/32)           // 12800 bitmask words per sample
#define MAXPIL 12000
#define MAXPTS 100
#define SCAN_BLK 256
#define NBLKA (NWORD/SCAN_BLK)     // 50 scan blocks per sample

typedef unsigned short u16;
typedef unsigned int   u32;

// ---- bf16 round-trip (RTNE) — used ONLY for the pillar-id value write ----
__device__ __forceinline__ float bf16rt(float f) {
    u32 u = __builtin_bit_cast(u32, f);
    u32 r = ((u + 0x7FFFu + ((u >> 16) & 1u)) >> 16) << 16;
    return __builtin_bit_cast(float, r);
}

// value barrier: blocks -ffp-contract=fast from fusing mul into the following sub
__device__ __forceinline__ float opaquef(float x) { asm volatile("" : "+v"(x)); return x; }

// XLA constant-folded reciprocals (verified rounding by hand):
//   1/f32(102.4) rounds to exactly 0.009765625f (5/512)
//   1/f32(0.32f/102.4f) = 320*(1+2^-24) -> rounds UP to 320 + 2^-15
#define R102 0.009765625f
#define RWH  320.000030517578125f          // 0x1.400002p8
__device__ __host__ constexpr float WH_N_C() { return (2.0f*0.16f)/(51.2f-(-51.2f)); }

// XLA sequence: t=2*(v+51.2); p=t*R102 (rounded); xn=p-1 (rounded separately!)
__device__ __forceinline__ float norm_x(float v) {
    float p = 2.0f*(v + 51.2f) * R102;
    return opaquef(p) - 1.0f;
}
// z: divide by 8 == multiply by exact 0.125 — identical either way
__device__ __forceinline__ float norm_z(float v) {
    float p = 2.0f*(v + 5.0f) * 0.125f;
    return opaquef(p) - 1.0f;
}

__device__ __forceinline__ int cell_of(float xn, float yn) {
    float fx = fminf(fmaxf(floorf((xn + 1.0f) * RWH), 0.0f), 639.0f);  // fmax = inert safety clamp
    float fy = fminf(fmaxf(floorf((yn + 1.0f) * RWH), 0.0f), 639.0f);
    return (int)fy * GRID_X + (int)fx;
}

// ---- K0: zero occMask+slotCnt; pillar ids -> -1.0f; slotCell -> -1 ----
__global__ void k_init(int4* __restrict__ zero4, int nz4,
                       float* __restrict__ pillars_f, int* __restrict__ slotCell, int npil) {
    int i = blockIdx.x*blockDim.x + threadIdx.x;
    if (i < nz4) zero4[i] = make_int4(0,0,0,0);
    if (i < npil) { pillars_f[i] = -1.0f; slotCell[i] = -1; }
}

// ---- K1: per-point cell id (cached to ws) + occupancy bitmask ----
__global__ void k_mask(const float4* __restrict__ pc, int P, u32* __restrict__ occMask,
                       int* __restrict__ cellId) {
    int i = blockIdx.x*blockDim.x + threadIdx.x;
    if (i >= NB*P) return;
    float4 pt = pc[i];
    int cell = cell_of(norm_x(pt.x), norm_x(pt.y));
    cellId[i] = cell;
    int b = i / P;
    atomicOr(&occMask[b*NWORD + (cell >> 5)], 1u << (cell & 31));
}

// ---- K2a: per-256-word popcount block sums (raw, not scanned) ----
__global__ void k_scanA(const u32* __restrict__ occMask, int* __restrict__ scanBlk) {
    __shared__ int lds[SCAN_BLK];
    int blk = blockIdx.x % NBLKA;
    int b   = blockIdx.x / NBLKA;
    int w   = blk*SCAN_BLK + threadIdx.x;
    lds[threadIdx.x] = __popc(occMask[b*NWORD + w]);
    __syncthreads();
    for (int d = SCAN_BLK/2; d > 0; d >>= 1) {
        if (threadIdx.x < d) lds[threadIdx.x] += lds[threadIdx.x + d];
        __syncthreads();
    }
    if (threadIdx.x == 0) scanBlk[b*NBLKA + blk] = lds[0];
}

// ---- K2c (fused B+C): per-block base computed in-block from raw sums;
//      per-word exclusive prefix; emit sorted pillar ids + exact cells ----
__global__ void k_scanC(const u32* __restrict__ occMask, const int* __restrict__ scanBlk,
                        int* __restrict__ wordPrefix, float* __restrict__ pillars_f,
                        int* __restrict__ slotCell) {
    __shared__ int lds[SCAN_BLK];
    __shared__ int sBlk[NBLKA];
    int blk = blockIdx.x % NBLKA;
    int b   = blockIdx.x / NBLKA;
    int tid = threadIdx.x;
    int w   = blk*SCAN_BLK + tid;
    if (tid < NBLKA) sBlk[tid] = scanBlk[b*NBLKA + tid];
    u32 m = occMask[b*NWORD + w];
    int pop = __popc(m);
    lds[tid] = pop;
    __syncthreads();
    for (int d = 1; d < SCAN_BLK; d <<= 1) {
        int t = (tid >= d) ? lds[tid - d] : 0;
        __syncthreads();
        lds[tid] += t;
        __syncthreads();
    }
    int base = 0;
    for (int i = 0; i < blk; i++) base += sBlk[i];   // <=49 LDS reads, all lanes same -> broadcast
    int prefix = base + lds[tid] - pop;              // exclusive
    wordPrefix[b*NWORD + w] = prefix;
    int wbase = w << 5;
    int slot = prefix;
    while (m) {
        int bit = __ffs(m) - 1;
        m &= m - 1;
        if (slot < MAXPIL) {
            int cell = wbase + bit;
            slotCell[b*MAXPIL + slot] = cell;
            pillars_f[b*MAXPIL + slot] = bf16rt((float)cell);  // match bf16-cast expected exactly
        }
        slot++;
    }
}

// ---- K3: scatter point indices into per-pillar lists (uses cached cellId) ----
__global__ void k_scatter(int P, const u32* __restrict__ occMask,
                          const int* __restrict__ wordPrefix, const int* __restrict__ cellId,
                          int* __restrict__ slotCnt, u16* __restrict__ idx16) {
    int i = blockIdx.x*blockDim.x + threadIdx.x;
    if (i >= NB*P) return;
    int b = i / P;
    int p = i - b*P;
    int cell = cellId[i];
    int w = cell >> 5, bit = cell & 31;
    u32 m = occMask[b*NWORD + w];
    int slot = wordPrefix[b*NWORD + w] + __popc(m & ((1u << bit) - 1u));
    if (slot >= MAXPIL) return;
    int g = b*MAXPIL + slot;
    int pos = atomicAdd(&slotCnt[g], 1);
    if (pos < MAXPTS) idx16[(size_t)g*MAXPTS + pos] = (u16)p;
}

// ---- K4: one wave per pillar: rank by index, build 100x9 f32 tile, dump ----
__global__ __launch_bounds__(64) void k_write(const float4* __restrict__ pc, int P,
                        const int* __restrict__ slotCell, const int* __restrict__ slotCnt,
                        const u16* __restrict__ idx16, float* __restrict__ out) {
    __shared__ __align__(16) float tile[MAXPTS*9];   // 900 f32 = 3600 B
    __shared__ int sIdx[MAXPTS];
    __shared__ float sx[MAXPTS], sy[MAXPTS], sz[MAXPTS], sr[MAXPTS];
    int g = blockIdx.x;                 // b*MAXPIL + slot
    int b = g / MAXPIL;
    int lane = threadIdx.x;
    float4* out4 = (float4*)out + (size_t)g*225;   // 225 x 16B per pillar
    int u = slotCell[g];
    if (u < 0) {                        // empty pillar: pure zero fill
        float4 z = make_float4(0.f,0.f,0.f,0.f);
        for (int i = lane; i < 225; i += 64) out4[i] = z;
        return;
    }
    int ntot = slotCnt[g];
    int n = min(ntot, MAXPTS);          // points/pillar ~5 here, so n == ntot

    float4* t4 = (float4*)tile;
    for (int i = lane; i < 225; i += 64) t4[i] = make_float4(0.f,0.f,0.f,0.f);

    // gather + normalize + local mean partials
    float ax = 0.f, ay = 0.f, az = 0.f;
    for (int j = lane; j < n; j += 64) {
        int p = idx16[(size_t)g*MAXPTS + j];
        sIdx[j] = p;
        float4 pt = pc[b*P + p];
        float xn = norm_x(pt.x);
        float yn = norm_x(pt.y);
        float zn = norm_z(pt.z);
        sx[j] = xn; sy[j] = yn; sz[j] = zn; sr[j] = pt.w;
        ax += xn; ay += yn; az += zn;
    }
    // wave-reduce means (f32; feature threshold is generous)
    for (int msk = 1; msk < 64; msk <<= 1) {
        ax += __shfl_xor(ax, msk);
        ay += __shfl_xor(ay, msk);
        az += __shfl_xor(az, msk);
    }
    float den = (float)max(ntot, 1);
    float mx = ax/den, my = ay/den, mz = az/den;
    const float wh = WH_N_C();
    float cx = -1.0f + (float)(u % GRID_X)*wh + wh*0.5f;
    float cy = -1.0f + (float)(u / GRID_X)*wh + wh*0.5f;
    __syncthreads();

    for (int j = lane; j < n; j += 64) {
        int p = sIdx[j];
        int rk = 0;                     // rank by original point index (stable order)
        for (int k = 0; k < n; k++) rk += (sIdx[k] < p) ? 1 : 0;
        float xn = sx[j], yn = sy[j], zn = sz[j];
        float* e = &tile[rk*9];
        e[0] = xn; e[1] = yn; e[2] = zn; e[3] = sr[j];
        e[4] = fabsf(xn - mx); e[5] = fabsf(yn - my); e[6] = fabsf(zn - mz);
        e[7] = cx - xn; e[8] = cy - yn;
    }
    __syncthreads();
    for (int i = lane; i < 225; i += 64) out4[i] = t4[i];
}

extern "C" void kernel_launch(void* const* d_in, const int* in_sizes, int n_in,
                              void* d_out, int out_size, void* d_ws, size_t ws_size,
                              hipStream_t stream) {
    const float4* pc = (const float4*)d_in[0];     // f32 x4 per point
    int P = in_sizes[0] / (NB*4);                  // 50000
    float* out = (float*)d_out;                    // f32 output buffer
    float* pillars_f = out + (size_t)NB*MAXPIL*MAXPTS*9;  // second tuple output (f32)

    // workspace layout (~11.2 MB total, int units) — stay well under ws_size
    u32* occMask   = (u32*)d_ws;                        // NB*NWORD      = 51200
    int* slotCnt   = (int*)(occMask + NB*NWORD);        // NB*MAXPIL     = 48000  [zero region ends]
    int* wordPrefix= slotCnt + NB*MAXPIL;               // NB*NWORD      = 51200
    int* scanBlk   = wordPrefix + NB*NWORD;             // NB*NBLKA(200) -> pad 256
    int* slotCell  = scanBlk + 256;                     // NB*MAXPIL     = 48000
    int* cellId    = slotCell + NB*MAXPIL;              // NB*P          = 200000
    u16* idx16     = (u16*)(cellId + NB*P);             // NB*MAXPIL*MAXPTS u16 = 9.6 MB

    int nzero = NB*NWORD + NB*MAXPIL;                   // 99200 ints, /4 = 24800 int4
    int nz4 = nzero / 4;
    int initThreads = nz4 > NB*MAXPIL ? nz4 : NB*MAXPIL;

    k_init<<<(initThreads+255)/256, 256, 0, stream>>>((int4*)occMask, nz4, pillars_f, slotCell, NB*MAXPIL);
    k_mask<<<(NB*P+255)/256, 256, 0, stream>>>(pc, P, occMask, cellId);
    k_scanA<<<NB*NBLKA, SCAN_BLK, 0, stream>>>(occMask, scanBlk);
    k_scanC<<<NB*NBLKA, SCAN_BLK, 0, stream>>>(occMask, scanBlk, wordPrefix, pillars_f, slotCell);
    k_scatter<<<(NB*P+255)/256, 256, 0, stream>>>(P, occMask, wordPrefix, cellId, slotCnt, idx16);
    k_write<<<NB*MAXPIL, 64, 0, stream>>>(pc, P, slotCell, slotCnt, idx16, out);
}

// Round 3
// 224.372 us; speedup vs baseline: 1.2062x; 1.0050x over previous
//
#include <hip/hip_runtime.h>

#define NB 4                 // batch
#define GRID_X 640
#define NCELL (GRID_X*GRID_X)      // 409600
#define NWORD (NCELL/32)           // 12800 bitmask words per sample
#define MAXPIL 12000
#define MAXPTS 100
#define SCAN_BLK 256
#define NBLKA (NWORD/SCAN_BLK)     // 50 scan blocks per sample

typedef unsigned short u16;
typedef unsigned int   u32;

// ---- bf16 round-trip (RTNE) — used ONLY for the pillar-id value write ----
__device__ __forceinline__ float bf16rt(float f) {
    u32 u = __builtin_bit_cast(u32, f);
    u32 r = ((u + 0x7FFFu + ((u >> 16) & 1u)) >> 16) << 16;
    return __builtin_bit_cast(float, r);
}

// value barrier: blocks -ffp-contract=fast from fusing mul into the following sub
__device__ __forceinline__ float opaquef(float x) { asm volatile("" : "+v"(x)); return x; }

// XLA constant-folded reciprocals (verified rounding by hand):
//   1/f32(102.4) rounds to exactly 0.009765625f (5/512)
//   1/f32(0.32f/102.4f) = 320*(1+2^-24) -> rounds UP to 320 + 2^-15
#define R102 0.009765625f
#define RWH  320.000030517578125f          // 0x1.400002p8
__device__ __host__ constexpr float WH_N_C() { return (2.0f*0.16f)/(51.2f-(-51.2f)); }

// XLA sequence: t=2*(v+51.2); p=t*R102 (rounded); xn=p-1 (rounded separately!)
__device__ __forceinline__ float norm_x(float v) {
    float p = 2.0f*(v + 51.2f) * R102;
    return opaquef(p) - 1.0f;
}
// z: divide by 8 == multiply by exact 0.125 — identical either way
__device__ __forceinline__ float norm_z(float v) {
    float p = 2.0f*(v + 5.0f) * 0.125f;
    return opaquef(p) - 1.0f;
}

__device__ __forceinline__ int cell_of(float xn, float yn) {
    float fx = fminf(fmaxf(floorf((xn + 1.0f) * RWH), 0.0f), 639.0f);  // fmax = inert safety clamp
    float fy = fminf(fmaxf(floorf((yn + 1.0f) * RWH), 0.0f), 639.0f);
    return (int)fy * GRID_X + (int)fx;
}

// ---- K0: zero occMask+slotCnt; pillar ids -> -1.0f; slotCell -> -1 ----
__global__ void k_init(int4* __restrict__ zero4, int nz4,
                       float* __restrict__ pillars_f, int* __restrict__ slotCell, int npil) {
    int i = blockIdx.x*blockDim.x + threadIdx.x;
    if (i < nz4) zero4[i] = make_int4(0,0,0,0);
    if (i < npil) { pillars_f[i] = -1.0f; slotCell[i] = -1; }
}

// ---- K1: per-point cell id (cached to ws) + occupancy bitmask ----
__global__ void k_mask(const float4* __restrict__ pc, int P, u32* __restrict__ occMask,
                       int* __restrict__ cellId) {
    int i = blockIdx.x*blockDim.x + threadIdx.x;
    if (i >= NB*P) return;
    float4 pt = pc[i];
    int cell = cell_of(norm_x(pt.x), norm_x(pt.y));
    cellId[i] = cell;
    int b = i / P;
    atomicOr(&occMask[b*NWORD + (cell >> 5)], 1u << (cell & 31));
}

// ---- K2a: per-256-word popcount block sums (raw, not scanned) ----
__global__ void k_scanA(const u32* __restrict__ occMask, int* __restrict__ scanBlk) {
    __shared__ int lds[SCAN_BLK];
    int blk = blockIdx.x % NBLKA;
    int b   = blockIdx.x / NBLKA;
    int w   = blk*SCAN_BLK + threadIdx.x;
    lds[threadIdx.x] = __popc(occMask[b*NWORD + w]);
    __syncthreads();
    for (int d = SCAN_BLK/2; d > 0; d >>= 1) {
        if (threadIdx.x < d) lds[threadIdx.x] += lds[threadIdx.x + d];
        __syncthreads();
    }
    if (threadIdx.x == 0) scanBlk[b*NBLKA + blk] = lds[0];
}

// ---- K2c (fused B+C): per-block base computed in-block from raw sums;
//      per-word exclusive prefix; emit sorted pillar ids + exact cells ----
__global__ void k_scanC(const u32* __restrict__ occMask, const int* __restrict__ scanBlk,
                        int* __restrict__ wordPrefix, float* __restrict__ pillars_f,
                        int* __restrict__ slotCell) {
    __shared__ int lds[SCAN_BLK];
    __shared__ int sBlk[NBLKA];
    int blk = blockIdx.x % NBLKA;
    int b   = blockIdx.x / NBLKA;
    int tid = threadIdx.x;
    int w   = blk*SCAN_BLK + tid;
    if (tid < NBLKA) sBlk[tid] = scanBlk[b*NBLKA + tid];
    u32 m = occMask[b*NWORD + w];
    int pop = __popc(m);
    lds[tid] = pop;
    __syncthreads();
    for (int d = 1; d < SCAN_BLK; d <<= 1) {
        int t = (tid >= d) ? lds[tid - d] : 0;
        __syncthreads();
        lds[tid] += t;
        __syncthreads();
    }
    int base = 0;
    for (int i = 0; i < blk; i++) base += sBlk[i];   // <=49 LDS reads, all lanes same -> broadcast
    int prefix = base + lds[tid] - pop;              // exclusive
    wordPrefix[b*NWORD + w] = prefix;
    int wbase = w << 5;
    int slot = prefix;
    while (m) {
        int bit = __ffs(m) - 1;
        m &= m - 1;
        if (slot < MAXPIL) {
            int cell = wbase + bit;
            slotCell[b*MAXPIL + slot] = cell;
            pillars_f[b*MAXPIL + slot] = bf16rt((float)cell);  // match bf16-cast expected exactly
        }
        slot++;
    }
}

// ---- K3: scatter point indices into per-pillar lists (uses cached cellId) ----
__global__ void k_scatter(int P, const u32* __restrict__ occMask,
                          const int* __restrict__ wordPrefix, const int* __restrict__ cellId,
                          int* __restrict__ slotCnt, u16* __restrict__ idx16) {
    int i = blockIdx.x*blockDim.x + threadIdx.x;
    if (i >= NB*P) return;
    int b = i / P;
    int p = i - b*P;
    int cell = cellId[i];
    int w = cell >> 5, bit = cell & 31;
    u32 m = occMask[b*NWORD + w];
    int slot = wordPrefix[b*NWORD + w] + __popc(m & ((1u << bit) - 1u));
    if (slot >= MAXPIL) return;
    int g = b*MAXPIL + slot;
    int pos = atomicAdd(&slotCnt[g], 1);
    if (pos < MAXPTS) idx16[(size_t)g*MAXPTS + pos] = (u16)p;
}

// ---- K4 v2: one wave per pillar. Ranks are a dense permutation of 0..n-1,
//      so rows [0,n) are data and rows [n,100) are zeros: write both straight
//      to global — no 900-float LDS tile, no tile zeroing, one barrier. ----
__global__ __launch_bounds__(64) void k_write(const float4* __restrict__ pc, int P,
                        const int* __restrict__ slotCell, const int* __restrict__ slotCnt,
                        const u16* __restrict__ idx16, float* __restrict__ out) {
    __shared__ int   sIdx[MAXPTS];
    __shared__ float sx[MAXPTS], sy[MAXPTS], sz[MAXPTS], sr[MAXPTS];
    int g = blockIdx.x;                 // b*MAXPIL + slot
    int b = g / MAXPIL;
    int lane = threadIdx.x;
    float*  o  = out + (size_t)g*900;   // 900 f32 per pillar
    float4* o4 = (float4*)o;            // 225 x 16B, 16B-aligned
    int u = slotCell[g];
    if (u < 0) {                        // empty pillar: pure zero fill
        float4 z = make_float4(0.f,0.f,0.f,0.f);
        for (int i = lane; i < 225; i += 64) o4[i] = z;
        return;
    }
    int ntot = slotCnt[g];
    int n = min(ntot, MAXPTS);          // points/pillar ~5 here, so n == ntot

    // gather + normalize + local mean partials
    float ax = 0.f, ay = 0.f, az = 0.f;
    for (int j = lane; j < n; j += 64) {
        int p = idx16[(size_t)g*MAXPTS + j];
        sIdx[j] = p;
        float4 pt = pc[b*P + p];
        float xn = norm_x(pt.x);
        float yn = norm_x(pt.y);
        float zn = norm_z(pt.z);
        sx[j] = xn; sy[j] = yn; sz[j] = zn; sr[j] = pt.w;
        ax += xn; ay += yn; az += zn;
    }
    // wave-reduce means (f32; feature threshold is generous)
    for (int msk = 1; msk < 64; msk <<= 1) {
        ax += __shfl_xor(ax, msk);
        ay += __shfl_xor(ay, msk);
        az += __shfl_xor(az, msk);
    }
    float den = (float)max(ntot, 1);
    float mx = ax/den, my = ay/den, mz = az/den;
    const float wh = WH_N_C();
    float cx = -1.0f + (float)(u % GRID_X)*wh + wh*0.5f;
    float cy = -1.0f + (float)(u / GRID_X)*wh + wh*0.5f;
    __syncthreads();                    // sIdx/s* visible across wave

    // data rows: each active lane writes its point's 9 floats at row rk
    for (int j = lane; j < n; j += 64) {
        int p = sIdx[j];
        int rk = 0;                     // rank by original point index (stable order)
        for (int k = 0; k < n; k++) rk += (sIdx[k] < p) ? 1 : 0;
        float xn = sx[j], yn = sy[j], zn = sz[j];
        float* e = o + rk*9;
        e[0] = xn; e[1] = yn; e[2] = zn; e[3] = sr[j];
        e[4] = fabsf(xn - mx); e[5] = fabsf(yn - my); e[6] = fabsf(zn - mz);
        e[7] = cx - xn; e[8] = cy - yn;
    }
    // zero rows [n,100): dwords [n*9, 900) — disjoint from data, no barrier needed
    int first = n*9;
    int a4 = (first + 3) & ~3;          // next 16B-aligned dword
    if (first + lane < a4) o[first + lane] = 0.0f;        // <=3 alignment dwords
    float4 z = make_float4(0.f,0.f,0.f,0.f);
    for (int i = a4/4 + lane; i < 225; i += 64) o4[i] = z;
}

extern "C" void kernel_launch(void* const* d_in, const int* in_sizes, int n_in,
                              void* d_out, int out_size, void* d_ws, size_t ws_size,
                              hipStream_t stream) {
    const float4* pc = (const float4*)d_in[0];     // f32 x4 per point
    int P = in_sizes[0] / (NB*4);                  // 50000
    float* out = (float*)d_out;                    // f32 output buffer
    float* pillars_f = out + (size_t)NB*MAXPIL*MAXPTS*9;  // second tuple output (f32)

    // workspace layout (~11.2 MB total, int units) — stay well under ws_size
    u32* occMask   = (u32*)d_ws;                        // NB*NWORD      = 51200
    int* slotCnt   = (int*)(occMask + NB*NWORD);        // NB*MAXPIL     = 48000  [zero region ends]
    int* wordPrefix= slotCnt + NB*MAXPIL;               // NB*NWORD      = 51200
    int* scanBlk   = wordPrefix + NB*NWORD;             // NB*NBLKA(200) -> pad 256
    int* slotCell  = scanBlk + 256;                     // NB*MAXPIL     = 48000
    int* cellId    = slotCell + NB*MAXPIL;              // NB*P          = 200000
    u16* idx16     = (u16*)(cellId + NB*P);             // NB*MAXPIL*MAXPTS u16 = 9.6 MB

    int nzero = NB*NWORD + NB*MAXPIL;                   // 99200 ints, /4 = 24800 int4
    int nz4 = nzero / 4;
    int initThreads = nz4 > NB*MAXPIL ? nz4 : NB*MAXPIL;

    k_init<<<(initThreads+255)/256, 256, 0, stream>>>((int4*)occMask, nz4, pillars_f, slotCell, NB*MAXPIL);
    k_mask<<<(NB*P+255)/256, 256, 0, stream>>>(pc, P, occMask, cellId);
    k_scanA<<<NB*NBLKA, SCAN_BLK, 0, stream>>>(occMask, scanBlk);
    k_scanC<<<NB*NBLKA, SCAN_BLK, 0, stream>>>(occMask, scanBlk, wordPrefix, pillars_f, slotCell);
    k_scatter<<<(NB*P+255)/256, 256, 0, stream>>>(P, occMask, wordPrefix, cellId, slotCnt, idx16);
    k_write<<<NB*MAXPIL, 64, 0, stream>>>(pc, P, slotCell, slotCnt, idx16, out);
}